// Round 2
// baseline (199.879 us; speedup 1.0000x reference)
//
#include <hip/hip_runtime.h>
#include <hip/hip_cooperative_groups.h>
#include <math.h>

namespace cg = cooperative_groups;

// PureCartesianE3Conv on MI355X — round 10.
// r9 post-mortem: 88us total, no single kernel dominates (all <44us); the
// pipeline is launch/latency-bound across 6 dependent launches.
// r10: (a) setup+count+scan+scatter merged into ONE cooperative kernel with
// grid.sync() phases; count blocks cache edst/esrc/pair-id + pair histogram
// in LDS and the SAME blocks run scatter after the sync (no re-gather, no
// re-histogram). (b) SCHUNK 1024->512 doubles count/scatter parallelism.
// (c) eslot deleted: einv=-1 now carries the padding flag for k_edge.
// Fallback: if cooperative launch errors, run the same phases as 4 regular
// launches (phases are shared __device__ functions; re-init is idempotent).

#define NPAIR 100
#define SCHUNK 512
#define TS 8192
#define NB_TAB (TS / 64)
#define LSCALE (8192.0f / 7.0f)
#define LSTEP  (7.0f / 8192.0f)

__device__ __forceinline__ float silu_acc(float x) {
    return x / (1.0f + expf(-x));   // precise: setup path only
}

// ================= phase device functions =================

__device__ void d_init(int blk, int tid, int N, int* nodecnt, int* paircnt) {
    int i = blk * 256 + tid;
    if (i < N) nodecnt[i] = 0;
    if (blk == 0 && tid < NPAIR) paircnt[tid] = 0;
}

__device__ void d_pairtab(int p, int tid, float* lds,
    const float* emb_table, const float* Wa1, const float* ba1,
    const float* Wa2, const float* ba2,
    const float* Wf3, const float* bf3,
    float* M, float* bM)
{
    int pa = p / 10, pb = p % 10;
    float* sh = lds;             // 128
    float* sP = lds + 128;       // 8
    if (tid < 128) {
        int row = (tid < 64) ? pa : pb;
        int j = tid & 63;
        float a = ba1[j];
#pragma unroll
        for (int k = 0; k < 16; ++k) a = fmaf(emb_table[row * 16 + k], Wa1[k * 64 + j], a);
        sh[tid] = silu_acc(a);
    }
    __syncthreads();
    if (tid < 8) {
        float aa = ba2[tid], ab = ba2[tid];
        for (int j = 0; j < 64; ++j) {
            aa = fmaf(sh[j], Wa2[j * 8 + tid], aa);
            ab = fmaf(sh[64 + j], Wa2[j * 8 + tid], ab);
        }
        sP[tid] = aa * ab;
    }
    __syncthreads();
    for (int base = tid; base < 3072; base += 256) {
        int h = base / 48;
        int j = base - h * 48;
        const float* wr = Wf3 + h * 1536 + (j >> 4) * 128 + (j & 15);
        float a = 0.0f;
#pragma unroll
        for (int c = 0; c < 8; ++c) a = fmaf(sP[c], wr[c * 16], a);
        M[p * 3072 + base] = a;
    }
    if (tid < 48) {
        const float* br = bf3 + (tid >> 4) * 128 + (tid & 15);
        float a = 0.0f;
#pragma unroll
        for (int c = 0; c < 8; ++c) a = fmaf(sP[c], br[c * 16], a);
        bM[p * 48 + tid] = a;
    }
}

__device__ void d_htab(int blk, int tid, float* lds,
    const float* Wf1, const float* bf1, const float* Wf2, const float* bf2,
    float* Htab)
{
    int w = __builtin_amdgcn_readfirstlane(tid >> 6);
    int lane = tid & 63;
    int s = blk * 64 + lane;
    float len = (float)s * LSTEP;
    float ek[8];
#pragma unroll
    for (int k = 0; k < 8; ++k) {
        float d = fmaf(len, 1.8f, -(float)(k + 1));
        ek[k] = expf(-d * d) * 2.5253813613805388f;   // sqrt(8)/1.12
    }
    float t[16];
    {
        const float* bq = bf1 + w * 16;
#pragma unroll
        for (int j = 0; j < 16; ++j) t[j] = bq[j];
#pragma unroll
        for (int k = 0; k < 8; ++k) {
            float e8 = ek[k];
            const float* wr = Wf1 + k * 64 + w * 16;
#pragma unroll
            for (int j = 0; j < 16; ++j) t[j] = fmaf(e8, wr[j], t[j]);
        }
#pragma unroll
        for (int j = 0; j < 16; ++j) lds[(w * 16 + j) * 64 + lane] = silu_acc(t[j]);
    }
    __syncthreads();
    float h2[16];
    {
        const float* bq = bf2 + w * 16;
#pragma unroll
        for (int j = 0; j < 16; ++j) h2[j] = bq[j];
    }
#pragma unroll 8
    for (int k = 0; k < 64; ++k) {
        float hk = lds[k * 64 + lane];
        const float* wr = Wf2 + k * 64 + w * 16;
#pragma unroll
        for (int j = 0; j < 16; ++j) h2[j] = fmaf(hk, wr[j], h2[j]);
    }
    float* tp = Htab + (size_t)s * 64 + w * 16;
#pragma unroll
    for (int j = 0; j < 16; ++j) tp[j] = silu_acc(h2[j]);
}

// LDS layout for count/scatter blocks (byte offsets into 16KB smem):
//   [0,2048)      edst_c[SCHUNK]
//   [2048,4096)   esrc_c[SCHUNK]
//   [4096,4608)   pv_c[SCHUNK]  (uint8 pair id)
//   [4608,5008)   hist[NPAIR]
//   [5008,5408)   cur[NPAIR]
//   [5408,5808)   gbase[NPAIR]
//   [8192,...)    scan scratch (sbuf[256] / off[NPAIR+1]) — disjoint

__device__ void d_count(int bid, int tid, char* sm,
    const int* esrc, const int* edst, const int* Aarr, int E,
    int* nodecnt, int* paircnt)
{
    int* edst_c = (int*)sm;
    int* esrc_c = (int*)(sm + 4 * SCHUNK);
    unsigned char* pv_c = (unsigned char*)(sm + 8 * SCHUNK);
    int* hist = (int*)(sm + 9 * SCHUNK);
    if (tid < NPAIR) hist[tid] = 0;
    __syncthreads();
    int base = bid * SCHUNK;
#pragma unroll
    for (int i = 0; i < SCHUNK / 256; ++i) {
        int idx = tid + i * 256;
        int e = base + idx;
        int d = -1, s = 0, p = 0;
        if (e < E) {
            d = edst[e];
            s = esrc[e];
            p = Aarr[s] * 10 + Aarr[d];
            atomicAdd(&nodecnt[d], 1);
            atomicAdd(&hist[p], 1);
        }
        edst_c[idx] = d;
        esrc_c[idx] = s;
        pv_c[idx] = (unsigned char)p;
    }
    __syncthreads();
    if (tid < NPAIR && hist[tid] > 0) atomicAdd(&paircnt[tid], hist[tid]);
}

__device__ void d_scan_nodes(int tid, char* sm, const int* nodecnt, int N,
                             int* row_off, int* ncur)
{
    int* sbuf = (int*)(sm + 8192);
    int CH = (N + 255) / 256;
    int start = tid * CH;
    int end = min(start + CH, N);
    int s = 0;
    for (int i = start; i < end; ++i) s += nodecnt[i];
    sbuf[tid] = s;
    __syncthreads();
    for (int o = 1; o < 256; o <<= 1) {
        int y = (tid >= o) ? sbuf[tid - o] : 0;
        __syncthreads();
        sbuf[tid] += y;
        __syncthreads();
    }
    int run = sbuf[tid] - s;
    for (int i = start; i < end; ++i) {
        row_off[i] = run;
        ncur[i] = run;
        run += nodecnt[i];
    }
    if (tid == 255) row_off[N] = sbuf[255];
}

__device__ void d_scan_pairs(int tid, char* sm, const int* paircnt, int* pcur,
                             int* b2p, int maxblk, int* einv, float* geo)
{
    int* off = (int*)(sm + 8192);
    if (tid == 0) {
        int run = 0;
        for (int p = 0; p < NPAIR; ++p) { off[p] = run; run += (paircnt[p] + 63) >> 6; }
        off[NPAIR] = run;
    }
    __syncthreads();
    for (int b = tid; b < maxblk; b += 256) b2p[b] = -1;
    __syncthreads();
    if (tid < NPAIR) {
        pcur[tid] = off[tid] * 64;
        for (int b = off[tid]; b < off[tid + 1]; ++b) b2p[b] = tid;
        int s = off[tid] * 64 + paircnt[tid];   // padding tail only
        int e2 = off[tid + 1] * 64;
        for (int q = s; q < e2; ++q) { einv[q] = -1; geo[q] = 0.0f; }
    }
}

template <bool CACHED>
__device__ void d_scatter(int bid, int tid, char* sm,
    const float* pos, const float* edge_shifts, const float* cell,
    const int* batch, const int* esrc, const int* edst, const int* Aarr, int E,
    int* ncur, int* pcur, int* einv, float* geo, float* v4)
{
    int* edst_c = (int*)sm;
    int* esrc_c = (int*)(sm + 4 * SCHUNK);
    unsigned char* pv_c = (unsigned char*)(sm + 8 * SCHUNK);
    int* hist = (int*)(sm + 9 * SCHUNK);
    int* cur = hist + NPAIR;
    int* gbase = cur + NPAIR;
    int base = bid * SCHUNK;
    if (!CACHED) {
        if (tid < NPAIR) hist[tid] = 0;
        __syncthreads();
#pragma unroll
        for (int i = 0; i < SCHUNK / 256; ++i) {
            int idx = tid + i * 256;
            int e = base + idx;
            int d = -1, s = 0, p = 0;
            if (e < E) {
                d = edst[e];
                s = esrc[e];
                p = Aarr[s] * 10 + Aarr[d];
                atomicAdd(&hist[p], 1);
            }
            edst_c[idx] = d;
            esrc_c[idx] = s;
            pv_c[idx] = (unsigned char)p;
        }
        __syncthreads();
    }
    if (tid < NPAIR) cur[tid] = 0;
    __syncthreads();
    if (tid < NPAIR && hist[tid] > 0) gbase[tid] = atomicAdd(&pcur[tid], hist[tid]);
    __syncthreads();
#pragma unroll
    for (int i = 0; i < SCHUNK / 256; ++i) {
        int idx = tid + i * 256;
        int d = edst_c[idx];
        if (d >= 0) {
            int e = base + idx;
            int p = pv_c[idx];
            int src = esrc_c[idx];
            int s2v = atomicAdd(&ncur[d], 1);
            int r = atomicAdd(&cur[p], 1);
            int slot = gbase[p] + r;
            einv[slot] = s2v;
            int b = batch[src];
            float s0 = edge_shifts[e * 3 + 0];
            float s1 = edge_shifts[e * 3 + 1];
            float s2 = edge_shifts[e * 3 + 2];
            const float* cm = cell + b * 9;
            float ev0 = pos[d * 3 + 0] - pos[src * 3 + 0] + s0 * cm[0] + s1 * cm[3] + s2 * cm[6];
            float ev1 = pos[d * 3 + 1] - pos[src * 3 + 1] + s0 * cm[1] + s1 * cm[4] + s2 * cm[7];
            float ev2 = pos[d * 3 + 2] - pos[src * 3 + 2] + s0 * cm[2] + s1 * cm[5] + s2 * cm[8];
            float len = sqrtf(ev0 * ev0 + ev1 * ev1 + ev2 * ev2);
            float inv = 1.0f / (len + 1e-12f);
            reinterpret_cast<float4*>(v4)[s2v] =
                make_float4(ev0 * inv, ev1 * inv, ev2 * inv, len);
            geo[slot] = len * LSCALE;
        }
    }
}

// ================= cooperative prep kernel =================

__global__ __launch_bounds__(256) void k_prep(
    int nbinit, int nhblk, int N, int E, int maxblk,
    int* nodecnt, int* paircnt, int* row_off, int* ncur, int* pcur,
    int* b2p, int* einv, float* geo, float* v4,
    const float* pos, const float* edge_shifts, const float* cell,
    const int* batch, const int* esrc, const int* edst, const int* Aarr,
    const float* emb_table, const float* Wa1, const float* ba1,
    const float* Wa2, const float* ba2,
    const float* Wf1, const float* bf1, const float* Wf2, const float* bf2,
    const float* Wf3, const float* bf3,
    float* M, float* bM, float* Htab)
{
    __shared__ __align__(16) char sm[16384];
    cg::grid_group grid = cg::this_grid();
    int bid = blockIdx.x;
    int tid = threadIdx.x;

    // phase 0: zero counters | pair table | radial table
    if (bid < nbinit) {
        d_init(bid, tid, N, nodecnt, paircnt);
    } else if (bid < nbinit + NPAIR) {
        d_pairtab(bid - nbinit, tid, (float*)sm, emb_table, Wa1, ba1, Wa2, ba2,
                  Wf3, bf3, M, bM);
    } else if (bid < nbinit + NPAIR + NB_TAB) {
        d_htab(bid - nbinit - NPAIR, tid, (float*)sm, Wf1, bf1, Wf2, bf2, Htab);
    }
    grid.sync();

    // phase 1: count (caches edst/esrc/pv + hist in LDS)
    if (bid < nhblk) d_count(bid, tid, sm, esrc, edst, Aarr, E, nodecnt, paircnt);
    grid.sync();

    // phase 2: scans
    if (bid == 0) d_scan_nodes(tid, sm, nodecnt, N, row_off, ncur);
    else if (bid == 1) d_scan_pairs(tid, sm, paircnt, pcur, b2p, maxblk, einv, geo);
    grid.sync();

    // phase 3: scatter using cached LDS state
    if (bid < nhblk)
        d_scatter<true>(bid, tid, sm, pos, edge_shifts, cell, batch,
                        esrc, edst, Aarr, E, ncur, pcur, einv, geo, v4);
}

// ================= fallback wrappers (regular launches) =================

__global__ __launch_bounds__(256) void k_setup_f(
    int nbinit, int N, int* nodecnt, int* paircnt,
    const float* emb_table, const float* Wa1, const float* ba1,
    const float* Wa2, const float* ba2,
    const float* Wf1, const float* bf1, const float* Wf2, const float* bf2,
    const float* Wf3, const float* bf3,
    float* M, float* bM, float* Htab)
{
    __shared__ __align__(16) char sm[16384];
    int bid = blockIdx.x, tid = threadIdx.x;
    if (bid < nbinit) d_init(bid, tid, N, nodecnt, paircnt);
    else if (bid < nbinit + NPAIR)
        d_pairtab(bid - nbinit, tid, (float*)sm, emb_table, Wa1, ba1, Wa2, ba2, Wf3, bf3, M, bM);
    else
        d_htab(bid - nbinit - NPAIR, tid, (float*)sm, Wf1, bf1, Wf2, bf2, Htab);
}

__global__ __launch_bounds__(256) void k_count_f(
    const int* esrc, const int* edst, const int* Aarr, int E,
    int* nodecnt, int* paircnt)
{
    __shared__ __align__(16) char sm[16384];
    d_count(blockIdx.x, threadIdx.x, sm, esrc, edst, Aarr, E, nodecnt, paircnt);
}

__global__ __launch_bounds__(256) void k_scan_f(
    const int* nodecnt, int N, int* row_off, int* ncur,
    const int* paircnt, int* pcur, int* b2p, int maxblk,
    int* einv, float* geo)
{
    __shared__ __align__(16) char sm[16384];
    if (blockIdx.x == 0) d_scan_nodes(threadIdx.x, sm, nodecnt, N, row_off, ncur);
    else d_scan_pairs(threadIdx.x, sm, paircnt, pcur, b2p, maxblk, einv, geo);
}

__global__ __launch_bounds__(256) void k_scatter_f(
    const float* pos, const float* edge_shifts, const float* cell,
    const int* batch, const int* esrc, const int* edst, const int* Aarr, int E,
    int* ncur, int* pcur, int* einv, float* geo, float* v4)
{
    __shared__ __align__(16) char sm[16384];
    d_scatter<false>(blockIdx.x, threadIdx.x, sm, pos, edge_shifts, cell, batch,
                     esrc, edst, Aarr, E, ncur, pcur, einv, geo, v4);
}

// ================= fused per-edge kernel =================

__global__ __launch_bounds__(256, 6) void k_edge(
    const int* __restrict__ b2p, const int* __restrict__ einv,
    const float* __restrict__ geo, const float* __restrict__ Htab,
    const float* __restrict__ M, const float* __restrict__ bM,
    float* __restrict__ gout)
{
    __shared__ float hbuf[64 * 64];  // 16 KB, [k][lane]
    int p = b2p[blockIdx.x];
    if (p < 0) return;
    p = __builtin_amdgcn_readfirstlane(p);
    int tid = threadIdx.x;
    int w = __builtin_amdgcn_readfirstlane(tid >> 6);  // wave id 0..3, SGPR
    int lane = tid & 63;
    int slot = blockIdx.x * 64 + lane;
    int ci = einv[slot];
    bool act = ci >= 0;

    // ---- fill hbuf via table gather + linear interp (wave w fills k in [w*16,+16)) ----
    float u = geo[slot];                       // len * LSCALE (0 for padding)
    int i0 = (int)u;
    i0 = min(max(i0, 0), TS - 2);
    float frac = u - (float)i0;
    const float4* r0 = reinterpret_cast<const float4*>(Htab + (size_t)i0 * 64 + w * 16);
    float4 ta[4], tb[4];
#pragma unroll
    for (int i = 0; i < 4; ++i) { ta[i] = r0[i]; tb[i] = r0[i + 16]; }  // +16 f4 = next row
    float* hb = hbuf + (w * 16) * 64 + lane;
#pragma unroll
    for (int i = 0; i < 4; ++i) {
        hb[(4 * i + 0) * 64] = fmaf(frac, tb[i].x - ta[i].x, ta[i].x);
        hb[(4 * i + 1) * 64] = fmaf(frac, tb[i].y - ta[i].y, ta[i].y);
        hb[(4 * i + 2) * 64] = fmaf(frac, tb[i].z - ta[i].z, ta[i].z);
        hb[(4 * i + 3) * 64] = fmaf(frac, tb[i].w - ta[i].w, ta[i].w);
    }
    __syncthreads();

    // ---- final slice: g[j in w*12..+12) = bM + h @ M  (M wave-uniform s_load) ----
    float g[12];
    {
        const float* bq = bM + p * 48 + w * 12;
#pragma unroll
        for (int j = 0; j < 12; ++j) g[j] = bq[j];
    }
    const float* __restrict__ mp = M + p * 3072 + w * 12;
#pragma unroll 8
    for (int h = 0; h < 64; ++h) {
        float hv = hbuf[h * 64 + lane];
        const float* wr = mp + h * 48;
#pragma unroll
        for (int j = 0; j < 12; ++j) g[j] = fmaf(hv, wr[j], g[j]);
    }

    if (act) {
        float4* gp = reinterpret_cast<float4*>(gout + (size_t)ci * 48 + w * 12);
#pragma unroll
        for (int i = 0; i < 3; ++i)
            gp[i] = make_float4(g[4 * i], g[4 * i + 1], g[4 * i + 2], g[4 * i + 3]);
    }
}

// ================= per-node aggregation =================

__global__ __launch_bounds__(256) void k_node(
    const int* __restrict__ row_off,
    const float* __restrict__ v4, const float* __restrict__ g,
    int N, float* __restrict__ out)
{
    int tid = threadIdx.x;
    int lane = tid & 63;
    int grp = lane >> 4;
    int o = lane & 15;
    int n = blockIdx.x * 4 + (tid >> 6);
    if (n >= N) return;
    int beg = row_off[n], end = row_off[n + 1];
    float a0 = 0.0f;
    float a1[3] = {0.0f, 0.0f, 0.0f};
    float a2[9] = {0.0f, 0.0f, 0.0f, 0.0f, 0.0f, 0.0f, 0.0f, 0.0f, 0.0f};
    for (int k = beg + grp; k < end; k += 4) {
        const float* ge = g + (size_t)k * 48;
        float g0 = ge[o];
        float g1 = ge[16 + o];
        float g2 = ge[32 + o];
        float4 vv = reinterpret_cast<const float4*>(v4)[k];
        float v[3] = {vv.x, vv.y, vv.z};
        a0 += g0;
#pragma unroll
        for (int d = 0; d < 3; ++d) a1[d] = fmaf(g1, v[d], a1[d]);
#pragma unroll
        for (int d1 = 0; d1 < 3; ++d1) {
            float gv = g2 * v[d1];
#pragma unroll
            for (int d2 = 0; d2 < 3; ++d2)
                a2[d1 * 3 + d2] = fmaf(gv, v[d2], a2[d1 * 3 + d2]);
        }
    }
#pragma unroll
    for (int m = 16; m <= 32; m <<= 1) {
        a0 += __shfl_xor(a0, m, 64);
#pragma unroll
        for (int d = 0; d < 3; ++d) a1[d] += __shfl_xor(a1[d], m, 64);
#pragma unroll
        for (int dd = 0; dd < 9; ++dd) a2[dd] += __shfl_xor(a2[dd], m, 64);
    }
    float cnt = (float)(end - beg);
    float invc = (cnt > 0.0f) ? (1.0f / cnt) : 1.0f;
    float* on = out + (size_t)n * 416;
    if (lane < 52)
        reinterpret_cast<float4*>(on + 208)[lane] = make_float4(0.f, 0.f, 0.f, 0.f);
    if (grp == 0) {
        on[o] = a0 * invc;
#pragma unroll
        for (int d = 0; d < 3; ++d) on[16 + o * 3 + d] = a1[d] * invc;
#pragma unroll
        for (int dd = 0; dd < 9; ++dd) on[64 + o * 9 + dd] = a2[dd] * invc;
    }
}

extern "C" void kernel_launch(void* const* d_in, const int* in_sizes, int n_in,
                              void* d_out, int out_size, void* d_ws, size_t ws_size,
                              hipStream_t stream)
{
    const float* pos         = (const float*)d_in[0];
    const float* edge_shifts = (const float*)d_in[1];
    const float* cell        = (const float*)d_in[2];
    const int*   Aarr        = (const int*)d_in[3];
    const int*   batch       = (const int*)d_in[4];
    const int*   esrc        = (const int*)d_in[5];
    const int*   edst        = (const int*)d_in[6];
    const float* emb_table   = (const float*)d_in[7];
    const float* Wa1         = (const float*)d_in[8];
    const float* ba1         = (const float*)d_in[9];
    const float* Wa2         = (const float*)d_in[10];
    const float* ba2         = (const float*)d_in[11];
    const float* Wf1         = (const float*)d_in[12];
    const float* bf1         = (const float*)d_in[13];
    const float* Wf2         = (const float*)d_in[14];
    const float* bf2         = (const float*)d_in[15];
    const float* Wf3         = (const float*)d_in[16];
    const float* bf3         = (const float*)d_in[17];

    int N = in_sizes[0] / 3;
    int E = in_sizes[5];
    int maxblk = (E + 63) / 64 + NPAIR;
    int nslot = maxblk * 64;
    int nhblk = (E + SCHUNK - 1) / SCHUNK;
    int nbinit = (N + 255) / 256;
    float* out = (float*)d_out;

    char* ws = (char*)d_ws;
    size_t off = 0;
    auto alloc = [&](size_t bytes) -> void* {
        void* p = ws + off;
        off += (bytes + 255) & ~(size_t)255;
        return p;
    };
    float* M       = (float*)alloc((size_t)NPAIR * 3072 * sizeof(float));
    float* bM      = (float*)alloc((size_t)NPAIR * 48 * sizeof(float));
    float* Htab    = (float*)alloc((size_t)TS * 64 * sizeof(float));
    int*   nodecnt = (int*)alloc((size_t)N * sizeof(int));
    int*   paircnt = (int*)alloc((size_t)NPAIR * sizeof(int));
    int*   rowoff  = (int*)alloc((size_t)(N + 1) * sizeof(int));
    int*   ncur    = (int*)alloc((size_t)N * sizeof(int));
    int*   pcur    = (int*)alloc((size_t)NPAIR * sizeof(int));
    int*   b2p     = (int*)alloc((size_t)maxblk * sizeof(int));
    int*   einv    = (int*)alloc((size_t)nslot * sizeof(int));
    float* geo     = (float*)alloc((size_t)nslot * sizeof(float));
    float* v4      = (float*)alloc((size_t)E * 4 * sizeof(float));
    float* g       = (float*)alloc((size_t)E * 48 * sizeof(float));
    (void)ws_size; (void)n_in; (void)out_size;

    int prep_grid = nbinit + NPAIR + NB_TAB;
    if (prep_grid < nhblk) prep_grid = nhblk;
    if (prep_grid < 2) prep_grid = 2;

    void* pargs[] = {
        &nbinit, &nhblk, &N, &E, &maxblk,
        (void*)&nodecnt, (void*)&paircnt, (void*)&rowoff, (void*)&ncur, (void*)&pcur,
        (void*)&b2p, (void*)&einv, (void*)&geo, (void*)&v4,
        (void*)&pos, (void*)&edge_shifts, (void*)&cell,
        (void*)&batch, (void*)&esrc, (void*)&edst, (void*)&Aarr,
        (void*)&emb_table, (void*)&Wa1, (void*)&ba1,
        (void*)&Wa2, (void*)&ba2,
        (void*)&Wf1, (void*)&bf1, (void*)&Wf2, (void*)&bf2,
        (void*)&Wf3, (void*)&bf3,
        (void*)&M, (void*)&bM, (void*)&Htab
    };
    hipError_t cerr = hipLaunchCooperativeKernel(
        (const void*)k_prep, dim3(prep_grid), dim3(256), pargs, 0, stream);
    if (cerr != hipSuccess) {
        (void)hipGetLastError();   // clear sticky error, run fallback pipeline
        k_setup_f<<<nbinit + NPAIR + NB_TAB, 256, 0, stream>>>(
            nbinit, N, nodecnt, paircnt, emb_table, Wa1, ba1, Wa2, ba2,
            Wf1, bf1, Wf2, bf2, Wf3, bf3, M, bM, Htab);
        k_count_f<<<nhblk, 256, 0, stream>>>(esrc, edst, Aarr, E, nodecnt, paircnt);
        k_scan_f<<<2, 256, 0, stream>>>(nodecnt, N, rowoff, ncur, paircnt, pcur,
                                        b2p, maxblk, einv, geo);
        k_scatter_f<<<nhblk, 256, 0, stream>>>(pos, edge_shifts, cell, batch,
                                               esrc, edst, Aarr, E, ncur, pcur,
                                               einv, geo, v4);
    }
    k_edge<<<maxblk, 256, 0, stream>>>(b2p, einv, geo, Htab, M, bM, g);
    k_node<<<(N + 3) / 4, 256, 0, stream>>>(rowoff, v4, g, N, out);
}

// Round 3
// 98.674 us; speedup vs baseline: 2.0257x; 2.0257x over previous
//
#include <hip/hip_runtime.h>
#include <math.h>

// PureCartesianE3Conv on MI355X — round 11.
// r10 post-mortem: cg::grid.sync() costs ~40us each on MI355X (cross-XCD L2
// flush) — k_prep sat at VALUBusy 1.5% for 145us. The launch boundary IS the
// cheap grid barrier here. Revert to separate launches, but restructure:
//   memset(nodecnt)                        - 40KB, trivial dispatch
//   k_front = pairtab | htab | count       - count captures per-edge ranks
//             (rnode via global atomic return, rp via LDS atomic return) and
//             per-block pair histograms -> slot assignment becomes pure.
//   k_mid   = scatter with ZERO atomics    - every block redundantly computes
//             the node prefix (10K ints, LDS) + pair/block prefix (~1-2us),
//             block 0 also writes row_off/b2p/padding. Kills the scan launch.
//   k_edge, k_node unchanged from r9/r10.
// 5 dispatches total (was 6 kernels in r9).

#define NPAIR 100
#define SCHUNK 512
#define TS 8192
#define NB_TAB (TS / 64)
#define LSCALE (8192.0f / 7.0f)
#define LSTEP  (7.0f / 8192.0f)
#define MAXN_LDS 10240   // problem fixes N_NODES = 10000

__device__ __forceinline__ float silu_acc(float x) {
    return x / (1.0f + expf(-x));   // precise: setup path only
}

// ================= phase device functions =================

__device__ void d_pairtab(int p, int tid, float* lds,
    const float* emb_table, const float* Wa1, const float* ba1,
    const float* Wa2, const float* ba2,
    const float* Wf3, const float* bf3,
    float* M, float* bM)
{
    int pa = p / 10, pb = p % 10;
    float* sh = lds;             // 128
    float* sP = lds + 128;       // 8
    if (tid < 128) {
        int row = (tid < 64) ? pa : pb;
        int j = tid & 63;
        float a = ba1[j];
#pragma unroll
        for (int k = 0; k < 16; ++k) a = fmaf(emb_table[row * 16 + k], Wa1[k * 64 + j], a);
        sh[tid] = silu_acc(a);
    }
    __syncthreads();
    if (tid < 8) {
        float aa = ba2[tid], ab = ba2[tid];
        for (int j = 0; j < 64; ++j) {
            aa = fmaf(sh[j], Wa2[j * 8 + tid], aa);
            ab = fmaf(sh[64 + j], Wa2[j * 8 + tid], ab);
        }
        sP[tid] = aa * ab;
    }
    __syncthreads();
    for (int base = tid; base < 3072; base += 256) {
        int h = base / 48;
        int j = base - h * 48;
        const float* wr = Wf3 + h * 1536 + (j >> 4) * 128 + (j & 15);
        float a = 0.0f;
#pragma unroll
        for (int c = 0; c < 8; ++c) a = fmaf(sP[c], wr[c * 16], a);
        M[p * 3072 + base] = a;
    }
    if (tid < 48) {
        const float* br = bf3 + (tid >> 4) * 128 + (tid & 15);
        float a = 0.0f;
#pragma unroll
        for (int c = 0; c < 8; ++c) a = fmaf(sP[c], br[c * 16], a);
        bM[p * 48 + tid] = a;
    }
}

__device__ void d_htab(int blk, int tid, float* lds,
    const float* Wf1, const float* bf1, const float* Wf2, const float* bf2,
    float* Htab)
{
    int w = __builtin_amdgcn_readfirstlane(tid >> 6);
    int lane = tid & 63;
    int s = blk * 64 + lane;
    float len = (float)s * LSTEP;
    float ek[8];
#pragma unroll
    for (int k = 0; k < 8; ++k) {
        float d = fmaf(len, 1.8f, -(float)(k + 1));
        ek[k] = expf(-d * d) * 2.5253813613805388f;   // sqrt(8)/1.12
    }
    float t[16];
    {
        const float* bq = bf1 + w * 16;
#pragma unroll
        for (int j = 0; j < 16; ++j) t[j] = bq[j];
#pragma unroll
        for (int k = 0; k < 8; ++k) {
            float e8 = ek[k];
            const float* wr = Wf1 + k * 64 + w * 16;
#pragma unroll
            for (int j = 0; j < 16; ++j) t[j] = fmaf(e8, wr[j], t[j]);
        }
#pragma unroll
        for (int j = 0; j < 16; ++j) lds[(w * 16 + j) * 64 + lane] = silu_acc(t[j]);
    }
    __syncthreads();
    float h2[16];
    {
        const float* bq = bf2 + w * 16;
#pragma unroll
        for (int j = 0; j < 16; ++j) h2[j] = bq[j];
    }
#pragma unroll 8
    for (int k = 0; k < 64; ++k) {
        float hk = lds[k * 64 + lane];
        const float* wr = Wf2 + k * 64 + w * 16;
#pragma unroll
        for (int j = 0; j < 16; ++j) h2[j] = fmaf(hk, wr[j], h2[j]);
    }
    float* tp = Htab + (size_t)s * 64 + w * 16;
#pragma unroll
    for (int j = 0; j < 16; ++j) tp[j] = silu_acc(h2[j]);
}

// ================= front kernel: pairtab | htab | count =================

__global__ __launch_bounds__(256) void k_front(
    int nhblk, int E,
    const int* __restrict__ esrc, const int* __restrict__ edst,
    const int* __restrict__ Aarr,
    int* __restrict__ nodecnt, int* __restrict__ blkhist,
    int* __restrict__ info_r, unsigned short* __restrict__ info_p,
    const float* __restrict__ emb_table, const float* __restrict__ Wa1,
    const float* __restrict__ ba1, const float* __restrict__ Wa2,
    const float* __restrict__ ba2,
    const float* __restrict__ Wf1, const float* __restrict__ bf1,
    const float* __restrict__ Wf2, const float* __restrict__ bf2,
    const float* __restrict__ Wf3, const float* __restrict__ bf3,
    float* __restrict__ M, float* __restrict__ bM, float* __restrict__ Htab)
{
    __shared__ __align__(16) char sm[16384];
    int bid = blockIdx.x;
    int tid = threadIdx.x;

    if (bid < NPAIR) {
        d_pairtab(bid, tid, (float*)sm, emb_table, Wa1, ba1, Wa2, ba2, Wf3, bf3, M, bM);
        return;
    }
    bid -= NPAIR;
    if (bid < NB_TAB) {
        d_htab(bid, tid, (float*)sm, Wf1, bf1, Wf2, bf2, Htab);
        return;
    }
    bid -= NB_TAB;

    // ---- count: rank capture + per-block pair histogram ----
    int* hist = (int*)sm;
    if (tid < NPAIR) hist[tid] = 0;
    __syncthreads();
    int base = bid * SCHUNK;
#pragma unroll
    for (int i = 0; i < SCHUNK / 256; ++i) {
        int e = base + tid + i * 256;
        if (e < E) {
            int d = edst[e];
            int s = esrc[e];
            int rn = atomicAdd(&nodecnt[d], 1);          // global rank within node
            int p = Aarr[s] * 10 + Aarr[d];
            int rp = atomicAdd(&hist[p], 1);             // rank within (block, pair)
            info_r[e] = rn;
            info_p[e] = (unsigned short)((rp << 7) | p); // rp<512 (9b), p<100 (7b)
        }
    }
    __syncthreads();
    if (tid < NPAIR) blkhist[tid * nhblk + bid] = hist[tid];
}

// ================= mid kernel: atomic-free scatter + redundant scans =================

__global__ __launch_bounds__(256) void k_mid(
    int nhblk, int N, int E, int maxblk,
    const int* __restrict__ esrc, const int* __restrict__ edst,
    const float* __restrict__ pos, const float* __restrict__ edge_shifts,
    const float* __restrict__ cell, const int* __restrict__ batch,
    const int* __restrict__ nodecnt, const int* __restrict__ blkhist,
    const int* __restrict__ info_r, const unsigned short* __restrict__ info_p,
    int* __restrict__ row_off, int* __restrict__ b2p,
    int* __restrict__ einv, float* __restrict__ geo, float* __restrict__ v4)
{
    __shared__ int roff[MAXN_LDS];   // node exclusive prefix (N <= MAXN_LDS)
    __shared__ int sscan[256];
    __shared__ int sblk[NPAIR];      // this block's base within pair p
    __shared__ int spb[NPAIR];       // global padded slot base of pair p
    __shared__ int stot[NPAIR];      // total edges of pair p
    __shared__ int susd;             // used slot-blocks
    int tid = threadIdx.x;
    int bid = blockIdx.x;

    // ---- node prefix scan (redundant per block, ~1us) ----
    for (int i = tid; i < N; i += 256) roff[i] = nodecnt[i];
    __syncthreads();
    int CH = (N + 255) / 256;
    int start = tid * CH, end = min(start + CH, N);
    int s = 0;
    for (int i = start; i < end; ++i) s += roff[i];
    sscan[tid] = s;
    __syncthreads();
    for (int o = 1; o < 256; o <<= 1) {
        int y = (tid >= o) ? sscan[tid - o] : 0;
        __syncthreads();
        sscan[tid] += y;
        __syncthreads();
    }
    int run = sscan[tid] - s;
    for (int i = start; i < end; ++i) { int c = roff[i]; roff[i] = run; run += c; }

    // ---- pair/block prefix (thread p scans its pair's per-block histogram) ----
    if (tid < NPAIR) {
        int t = 0, myb = 0;
        for (int b = 0; b < nhblk; ++b) {
            int h = blkhist[tid * nhblk + b];
            if (b == bid) myb = t;
            t += h;
        }
        stot[tid] = t;
        sblk[tid] = myb;
    }
    __syncthreads();
    if (tid == 0) {
        int run2 = 0;
        for (int p = 0; p < NPAIR; ++p) { spb[p] = run2 * 64; run2 += (stot[p] + 63) >> 6; }
        susd = run2;
    }
    __syncthreads();

    // ---- block 0 extra duties: publish row_off, b2p, slot padding ----
    if (bid == 0) {
        for (int i = tid; i < N; i += 256) row_off[i] = roff[i];
        if (tid == 0) row_off[N] = sscan[255];
        if (tid < NPAIR) {
            int ob = spb[tid] >> 6;
            int nb = (stot[tid] + 63) >> 6;
            for (int b = ob; b < ob + nb; ++b) b2p[b] = tid;
            int s0 = spb[tid] + stot[tid];
            int s1 = (ob + nb) * 64;
            for (int q = s0; q < s1; ++q) { einv[q] = -1; geo[q] = 0.0f; }
        }
        for (int b = susd + tid; b < maxblk; b += 256) b2p[b] = -1;
    }

    // ---- scatter: pure function, no atomics ----
    int base = bid * SCHUNK;
#pragma unroll
    for (int i = 0; i < SCHUNK / 256; ++i) {
        int e = base + tid + i * 256;
        if (e < E) {
            int d = edst[e];
            int src = esrc[e];
            int rn = info_r[e];
            int ip = (int)info_p[e];
            int p = ip & 127;
            int rp = ip >> 7;
            int s2v = roff[d] + rn;
            int slot = spb[p] + sblk[p] + rp;
            einv[slot] = s2v;
            int b = batch[src];
            float s0 = edge_shifts[e * 3 + 0];
            float s1 = edge_shifts[e * 3 + 1];
            float s2 = edge_shifts[e * 3 + 2];
            const float* cm = cell + b * 9;
            float ev0 = pos[d * 3 + 0] - pos[src * 3 + 0] + s0 * cm[0] + s1 * cm[3] + s2 * cm[6];
            float ev1 = pos[d * 3 + 1] - pos[src * 3 + 1] + s0 * cm[1] + s1 * cm[4] + s2 * cm[7];
            float ev2 = pos[d * 3 + 2] - pos[src * 3 + 2] + s0 * cm[2] + s1 * cm[5] + s2 * cm[8];
            float len = sqrtf(ev0 * ev0 + ev1 * ev1 + ev2 * ev2);
            float inv = 1.0f / (len + 1e-12f);
            reinterpret_cast<float4*>(v4)[s2v] =
                make_float4(ev0 * inv, ev1 * inv, ev2 * inv, len);
            geo[slot] = len * LSCALE;
        }
    }
}

// ================= fused per-edge kernel =================

__global__ __launch_bounds__(256, 6) void k_edge(
    const int* __restrict__ b2p, const int* __restrict__ einv,
    const float* __restrict__ geo, const float* __restrict__ Htab,
    const float* __restrict__ M, const float* __restrict__ bM,
    float* __restrict__ gout)
{
    __shared__ float hbuf[64 * 64];  // 16 KB, [k][lane]
    int p = b2p[blockIdx.x];
    if (p < 0) return;
    p = __builtin_amdgcn_readfirstlane(p);
    int tid = threadIdx.x;
    int w = __builtin_amdgcn_readfirstlane(tid >> 6);  // wave id 0..3, SGPR
    int lane = tid & 63;
    int slot = blockIdx.x * 64 + lane;
    int ci = einv[slot];
    bool act = ci >= 0;

    // ---- fill hbuf via table gather + linear interp (wave w fills k in [w*16,+16)) ----
    float u = geo[slot];                       // len * LSCALE (0 for padding)
    int i0 = (int)u;
    i0 = min(max(i0, 0), TS - 2);
    float frac = u - (float)i0;
    const float4* r0 = reinterpret_cast<const float4*>(Htab + (size_t)i0 * 64 + w * 16);
    float4 ta[4], tb[4];
#pragma unroll
    for (int i = 0; i < 4; ++i) { ta[i] = r0[i]; tb[i] = r0[i + 16]; }  // +16 f4 = next row
    float* hb = hbuf + (w * 16) * 64 + lane;
#pragma unroll
    for (int i = 0; i < 4; ++i) {
        hb[(4 * i + 0) * 64] = fmaf(frac, tb[i].x - ta[i].x, ta[i].x);
        hb[(4 * i + 1) * 64] = fmaf(frac, tb[i].y - ta[i].y, ta[i].y);
        hb[(4 * i + 2) * 64] = fmaf(frac, tb[i].z - ta[i].z, ta[i].z);
        hb[(4 * i + 3) * 64] = fmaf(frac, tb[i].w - ta[i].w, ta[i].w);
    }
    __syncthreads();

    // ---- final slice: g[j in w*12..+12) = bM + h @ M  (M wave-uniform s_load) ----
    float g[12];
    {
        const float* bq = bM + p * 48 + w * 12;
#pragma unroll
        for (int j = 0; j < 12; ++j) g[j] = bq[j];
    }
    const float* __restrict__ mp = M + p * 3072 + w * 12;
#pragma unroll 8
    for (int h = 0; h < 64; ++h) {
        float hv = hbuf[h * 64 + lane];
        const float* wr = mp + h * 48;
#pragma unroll
        for (int j = 0; j < 12; ++j) g[j] = fmaf(hv, wr[j], g[j]);
    }

    if (act) {
        float4* gp = reinterpret_cast<float4*>(gout + (size_t)ci * 48 + w * 12);
#pragma unroll
        for (int i = 0; i < 3; ++i)
            gp[i] = make_float4(g[4 * i], g[4 * i + 1], g[4 * i + 2], g[4 * i + 3]);
    }
}

// ================= per-node aggregation =================

__global__ __launch_bounds__(256) void k_node(
    const int* __restrict__ row_off,
    const float* __restrict__ v4, const float* __restrict__ g,
    int N, float* __restrict__ out)
{
    int tid = threadIdx.x;
    int lane = tid & 63;
    int grp = lane >> 4;
    int o = lane & 15;
    int n = blockIdx.x * 4 + (tid >> 6);
    if (n >= N) return;
    int beg = row_off[n], end = row_off[n + 1];
    float a0 = 0.0f;
    float a1[3] = {0.0f, 0.0f, 0.0f};
    float a2[9] = {0.0f, 0.0f, 0.0f, 0.0f, 0.0f, 0.0f, 0.0f, 0.0f, 0.0f};
    for (int k = beg + grp; k < end; k += 4) {
        const float* ge = g + (size_t)k * 48;
        float g0 = ge[o];
        float g1 = ge[16 + o];
        float g2 = ge[32 + o];
        float4 vv = reinterpret_cast<const float4*>(v4)[k];
        float v[3] = {vv.x, vv.y, vv.z};
        a0 += g0;
#pragma unroll
        for (int d = 0; d < 3; ++d) a1[d] = fmaf(g1, v[d], a1[d]);
#pragma unroll
        for (int d1 = 0; d1 < 3; ++d1) {
            float gv = g2 * v[d1];
#pragma unroll
            for (int d2 = 0; d2 < 3; ++d2)
                a2[d1 * 3 + d2] = fmaf(gv, v[d2], a2[d1 * 3 + d2]);
        }
    }
#pragma unroll
    for (int m = 16; m <= 32; m <<= 1) {
        a0 += __shfl_xor(a0, m, 64);
#pragma unroll
        for (int d = 0; d < 3; ++d) a1[d] += __shfl_xor(a1[d], m, 64);
#pragma unroll
        for (int dd = 0; dd < 9; ++dd) a2[dd] += __shfl_xor(a2[dd], m, 64);
    }
    float cnt = (float)(end - beg);
    float invc = (cnt > 0.0f) ? (1.0f / cnt) : 1.0f;
    float* on = out + (size_t)n * 416;
    if (lane < 52)
        reinterpret_cast<float4*>(on + 208)[lane] = make_float4(0.f, 0.f, 0.f, 0.f);
    if (grp == 0) {
        on[o] = a0 * invc;
#pragma unroll
        for (int d = 0; d < 3; ++d) on[16 + o * 3 + d] = a1[d] * invc;
#pragma unroll
        for (int dd = 0; dd < 9; ++dd) on[64 + o * 9 + dd] = a2[dd] * invc;
    }
}

extern "C" void kernel_launch(void* const* d_in, const int* in_sizes, int n_in,
                              void* d_out, int out_size, void* d_ws, size_t ws_size,
                              hipStream_t stream)
{
    const float* pos         = (const float*)d_in[0];
    const float* edge_shifts = (const float*)d_in[1];
    const float* cell        = (const float*)d_in[2];
    const int*   Aarr        = (const int*)d_in[3];
    const int*   batch       = (const int*)d_in[4];
    const int*   esrc        = (const int*)d_in[5];
    const int*   edst        = (const int*)d_in[6];
    const float* emb_table   = (const float*)d_in[7];
    const float* Wa1         = (const float*)d_in[8];
    const float* ba1         = (const float*)d_in[9];
    const float* Wa2         = (const float*)d_in[10];
    const float* ba2         = (const float*)d_in[11];
    const float* Wf1         = (const float*)d_in[12];
    const float* bf1         = (const float*)d_in[13];
    const float* Wf2         = (const float*)d_in[14];
    const float* bf2         = (const float*)d_in[15];
    const float* Wf3         = (const float*)d_in[16];
    const float* bf3         = (const float*)d_in[17];

    int N = in_sizes[0] / 3;
    int E = in_sizes[5];
    int maxblk = (E + 63) / 64 + NPAIR;
    int nslot = maxblk * 64;
    int nhblk = (E + SCHUNK - 1) / SCHUNK;
    float* out = (float*)d_out;

    char* ws = (char*)d_ws;
    size_t off = 0;
    auto alloc = [&](size_t bytes) -> void* {
        void* p = ws + off;
        off += (bytes + 255) & ~(size_t)255;
        return p;
    };
    float* M       = (float*)alloc((size_t)NPAIR * 3072 * sizeof(float));
    float* bM      = (float*)alloc((size_t)NPAIR * 48 * sizeof(float));
    float* Htab    = (float*)alloc((size_t)TS * 64 * sizeof(float));
    int*   nodecnt = (int*)alloc((size_t)N * sizeof(int));
    int*   rowoff  = (int*)alloc((size_t)(N + 1) * sizeof(int));
    int*   blkhist = (int*)alloc((size_t)NPAIR * nhblk * sizeof(int));
    int*   info_r  = (int*)alloc((size_t)E * sizeof(int));
    unsigned short* info_p = (unsigned short*)alloc((size_t)E * sizeof(unsigned short));
    int*   b2p     = (int*)alloc((size_t)maxblk * sizeof(int));
    int*   einv    = (int*)alloc((size_t)nslot * sizeof(int));
    float* geo     = (float*)alloc((size_t)nslot * sizeof(float));
    float* v4      = (float*)alloc((size_t)E * 4 * sizeof(float));
    float* g       = (float*)alloc((size_t)E * 48 * sizeof(float));
    (void)ws_size; (void)n_in; (void)out_size;

    hipMemsetAsync(nodecnt, 0, (size_t)N * sizeof(int), stream);
    k_front<<<NPAIR + NB_TAB + nhblk, 256, 0, stream>>>(
        nhblk, E, esrc, edst, Aarr, nodecnt, blkhist, info_r, info_p,
        emb_table, Wa1, ba1, Wa2, ba2, Wf1, bf1, Wf2, bf2, Wf3, bf3,
        M, bM, Htab);
    k_mid<<<nhblk, 256, 0, stream>>>(
        nhblk, N, E, maxblk, esrc, edst, pos, edge_shifts, cell, batch,
        nodecnt, blkhist, info_r, info_p, rowoff, b2p, einv, geo, v4);
    k_edge<<<maxblk, 256, 0, stream>>>(b2p, einv, geo, Htab, M, bM, g);
    k_node<<<(N + 3) / 4, 256, 0, stream>>>(rowoff, v4, g, N, out);
}